// Round 14
// baseline (821.802 us; speedup 1.0000x reference)
//
#include <hip/hip_runtime.h>
#include <hip/hip_bf16.h>

constexpr int kB  = 8;
constexpr int kC  = 256;
constexpr int kCq = 32;
constexpr int kH  = 96;
constexpr int kW  = 96;
constexpr int kP  = kH * kW;      // 9216

using bf16x8 = __attribute__((ext_vector_type(8))) short;
using bf16x4 = __attribute__((ext_vector_type(4))) short;
using f32x4  = __attribute__((ext_vector_type(4))) float;

// load 8 bf16 from 8B-aligned LDS as two b64 reads
__device__ inline bf16x8 ld_lds8(const __hip_bfloat16* p) {
    bf16x4 lo = *(const bf16x4*)p;
    bf16x4 hi = *(const bf16x4*)(p + 4);
    return __builtin_shufflevector(lo, hi, 0, 1, 2, 3, 4, 5, 6, 7);
}

// async 16B global->LDS copy (per-lane global addr, wave-uniform LDS base)
__device__ inline void async_copy16(const void* g, void* l) {
    __builtin_amdgcn_global_load_lds(
        (const __attribute__((address_space(1))) unsigned int*)g,
        (__attribute__((address_space(3))) unsigned int*)l, 16, 0, 0);
}

// ---------------------------------------------------------------------------
// Kernel W1: convert Wq+Wk -> Wqkb [64][256] bf16, Wv -> Wvb [256][256] bf16.
// ---------------------------------------------------------------------------
__global__ __launch_bounds__(256) void w_convert(
    const float* __restrict__ Wq, const float* __restrict__ Wk,
    const float* __restrict__ Wv,
    __hip_bfloat16* __restrict__ Wqkb, __hip_bfloat16* __restrict__ Wvb)
{
    const int i = blockIdx.x * 256 + threadIdx.x;
    if (i < 8192)       Wqkb[i] = __float2bfloat16(Wq[i]);
    else if (i < 16384) Wqkb[i] = __float2bfloat16(Wk[i - 8192]);
    else                Wvb[i - 16384] = __float2bfloat16(Wv[i - 16384]);
}

// ---------------------------------------------------------------------------
// Kernel A v6: q/k/v projection GEMM via bf16 MFMA.
// v6 = v5 minus the Vpm stores (Vpm's only consumer was pass2's VL staging,
// now replaced by Vcol direct reads). Saves 37.7 MB of stores per stream.
// ---------------------------------------------------------------------------
__global__ __launch_bounds__(256, 2) void qkv_mfma(
    const float* __restrict__ in_qk, const float* __restrict__ in_v,
    const __hip_bfloat16* __restrict__ Wqkb, const __hip_bfloat16* __restrict__ Wvb,
    const float* __restrict__ bq, const float* __restrict__ bk,
    const float* __restrict__ bv,
    __hip_bfloat16* __restrict__ Qbh, __hip_bfloat16* __restrict__ Qbl,
    __hip_bfloat16* __restrict__ Kbh, __hip_bfloat16* __restrict__ Kbl,
    __hip_bfloat16* __restrict__ Vhw)
{
    __shared__ __align__(16) char smem[34816];
    float* stg = (float*)smem;
    __hip_bfloat16* vt = (__hip_bfloat16*)smem;

    const int b = blockIdx.y, t = threadIdx.x;
    const int wv = t >> 6, l = t & 63;
    const int n = l & 15, q = l >> 4;
    const int p0 = blockIdx.x * 64;
    const int p  = p0 + wv * 16 + n;
    const size_t bP = (size_t)b * kP;

    const float* __restrict__ xq = in_qk + (size_t)b * kC * kP + p0;
    const float* __restrict__ xv = in_v  + (size_t)b * kC * kP + p0;

    f32x4 acc[20];
#pragma unroll
    for (int i = 0; i < 20; i++) acc[i] = (f32x4)0.f;

    const int lrow = l >> 4, lpx = (l & 15) * 4;
#define STAGE_CHUNK(kc, buf)                                                   \
    {                                                                          \
        const size_t cb = (size_t)(kc) * 32;                                   \
        float* dq = stg + (size_t)(buf) * 4096;                                \
        float* dv = dq + 2048;                                                 \
        _Pragma("unroll")                                                      \
        for (int j = 0; j < 2; j++) {                                          \
            const int r0 = wv * 8 + j * 4;                                     \
            async_copy16(&xq[(cb + r0 + lrow) * kP + lpx], &dq[r0 * 64]);      \
            async_copy16(&xv[(cb + r0 + lrow) * kP + lpx], &dv[r0 * 64]);      \
        }                                                                      \
    }

    STAGE_CHUNK(0, 0);
    __syncthreads();

    int cur = 0;
    for (int kc = 0; kc < 8; kc++) {
        if (kc < 7) STAGE_CHUNK(kc + 1, cur ^ 1);

        const int c0 = kc * 32 + q * 8;

        bf16x8 wq[4], wv2[16];
#pragma unroll
        for (int mt = 0; mt < 4; mt++)
            wq[mt] = *(const bf16x8*)(Wqkb + ((mt * 16 + n) << 8) + c0);
#pragma unroll
        for (int mt = 0; mt < 16; mt++)
            wv2[mt] = *(const bf16x8*)(Wvb + ((mt * 16 + n) << 8) + c0);

        const float* __restrict__ sqf = stg + (size_t)cur * 4096;
        const float* __restrict__ svf = sqf + 2048;
        const int pl = wv * 16 + n;
        union { bf16x8 v; __hip_bfloat16 h[8]; } bfq, bfv;
#pragma unroll
        for (int j = 0; j < 8; j++)
            bfq.h[j] = __float2bfloat16(sqf[(q * 8 + j) * 64 + pl]);
#pragma unroll
        for (int j = 0; j < 8; j++)
            bfv.h[j] = __float2bfloat16(svf[(q * 8 + j) * 64 + pl]);

#pragma unroll
        for (int mt = 0; mt < 4; mt++)
            acc[mt] = __builtin_amdgcn_mfma_f32_16x16x32_bf16(wq[mt], bfq.v, acc[mt], 0, 0, 0);
#pragma unroll
        for (int mt = 0; mt < 16; mt++)
            acc[4 + mt] = __builtin_amdgcn_mfma_f32_16x16x32_bf16(wv2[mt], bfv.v, acc[4 + mt], 0, 0, 0);

        __syncthreads();
        cur ^= 1;
    }
#undef STAGE_CHUNK

#pragma unroll
    for (int mt = 0; mt < 2; mt++) {
        float4 bias = *(const float4*)&bq[mt * 16 + q * 4];
        float vv[4] = { acc[mt][0] + bias.x, acc[mt][1] + bias.y,
                        acc[mt][2] + bias.z, acc[mt][3] + bias.w };
        union { ushort4 u; __hip_bfloat16 h[4]; } hi, lo;
#pragma unroll
        for (int r = 0; r < 4; r++) {
            __hip_bfloat16 h = __float2bfloat16(vv[r]);
            hi.h[r] = h;
            lo.h[r] = __float2bfloat16(vv[r] - __bfloat162float(h));
        }
        *(ushort4*)&Qbh[(bP + p) * kCq + mt * 16 + q * 4] = hi.u;
        *(ushort4*)&Qbl[(bP + p) * kCq + mt * 16 + q * 4] = lo.u;
    }
#pragma unroll
    for (int mt = 2; mt < 4; mt++) {
        float4 bias = *(const float4*)&bk[(mt - 2) * 16 + q * 4];
        float vv[4] = { acc[mt][0] + bias.x, acc[mt][1] + bias.y,
                        acc[mt][2] + bias.z, acc[mt][3] + bias.w };
        union { ushort4 u; __hip_bfloat16 h[4]; } hi, lo;
#pragma unroll
        for (int r = 0; r < 4; r++) {
            __hip_bfloat16 h = __float2bfloat16(vv[r]);
            hi.h[r] = h;
            lo.h[r] = __float2bfloat16(vv[r] - __bfloat162float(h));
        }
        *(ushort4*)&Kbh[(bP + p) * kCq + (mt - 2) * 16 + q * 4] = hi.u;
        *(ushort4*)&Kbl[(bP + p) * kCq + (mt - 2) * 16 + q * 4] = lo.u;
    }

    // ---- V: vt LDS transpose -> coalesced Vhw rows (no Vpm store) ----
#pragma unroll
    for (int mt = 0; mt < 16; mt++) {
        float4 bias = *(const float4*)&bv[mt * 16 + q * 4];
        float vv[4] = { acc[4 + mt][0] + bias.x, acc[4 + mt][1] + bias.y,
                        acc[4 + mt][2] + bias.z, acc[4 + mt][3] + bias.w };
#pragma unroll
        for (int r = 0; r < 4; r++)
            vt[(mt * 16 + q * 4 + r) * 68 + wv * 16 + n] = __float2bfloat16(vv[r]);
    }
    __syncthreads();

    {
        __hip_bfloat16* dst = Vhw + ((size_t)b * kC + t) * kP + p0;
#pragma unroll
        for (int j = 0; j < 8; j++) {
            bf16x8 row = ld_lds8(&vt[t * 68 + j * 8]);
            *(bf16x8*)&dst[j * 8] = row;
        }
    }
}

// ---------------------------------------------------------------------------
// Kernel T: per-(b,c) 96x96 transpose Vhw [c][h][w] -> Vcol [c][w][h].
// grid (kB*kC) = 2048, block 256. LDS tile [96][105] (pad breaks conflicts).
// Exact bf16 copy -> numerics unchanged.
// ---------------------------------------------------------------------------
__global__ __launch_bounds__(256) void vcol_tr(
    const __hip_bfloat16* __restrict__ Vhw, __hip_bfloat16* __restrict__ Vcol)
{
    __shared__ __hip_bfloat16 tile[96][105];
    const int bc = blockIdx.x;
    const size_t base = (size_t)bc * kP;
    const int t = threadIdx.x;

    for (int ci = t; ci < 1152; ci += 256) {
        const int off = ci * 8, h = off / 96, w = off - h * 96;
        union { bf16x8 v; __hip_bfloat16 e[8]; } in;
        in.v = *(const bf16x8*)&Vhw[base + off];
#pragma unroll
        for (int j = 0; j < 8; j++) tile[h][w + j] = in.e[j];
    }
    __syncthreads();
    for (int ci = t; ci < 1152; ci += 256) {
        const int off = ci * 8, w = off / 96, h = off - w * 96;
        union { bf16x8 v; __hip_bfloat16 e[8]; } o;
#pragma unroll
        for (int j = 0; j < 8; j++) o.e[j] = tile[h + j][w];
        *(bf16x8*)&Vcol[base + off] = o.v;
    }
}

// ---------------------------------------------------------------------------
// Kernel S: eH stats per column. grid (W, B), block 256.  (unchanged)
// ---------------------------------------------------------------------------
__global__ __launch_bounds__(256) void cc_stats(
    const __hip_bfloat16* __restrict__ Qbh, const __hip_bfloat16* __restrict__ Qbl,
    const __hip_bfloat16* __restrict__ Kbh, const __hip_bfloat16* __restrict__ Kbl,
    float* __restrict__ Sm, float* __restrict__ Si)
{
    __shared__ __align__(16) __hip_bfloat16 QH[96][36], QLo[96][36];
    __shared__ __align__(16) __hip_bfloat16 KH[96][36], KLo[96][36];
    __shared__ __align__(16) float EL[96][97];
    const int w = blockIdx.x, b = blockIdx.y;
    const int t = threadIdx.x;
    const size_t bP = (size_t)b * kP;

    for (int idx = t; idx < 768; idx += 256) {
        int row = idx >> 3, ch = (idx & 7) * 4;
        size_t g = (bP + (size_t)row * kW + w) * kCq + ch;
        *(ushort4*)&QH[row][ch]  = *(const ushort4*)&Qbh[g];
        *(ushort4*)&QLo[row][ch] = *(const ushort4*)&Qbl[g];
        *(ushort4*)&KH[row][ch]  = *(const ushort4*)&Kbh[g];
        *(ushort4*)&KLo[row][ch] = *(const ushort4*)&Kbl[g];
    }
    __syncthreads();

    const int wv = t >> 6, l = t & 63, ln = l & 15, lq = l >> 4;
#pragma unroll
    for (int s = 0; s < 9; s++) {
        int tile = wv * 9 + s, it = tile / 6, jt = tile % 6;
        bf16x8 ah = ld_lds8(&QH[it * 16 + ln][lq * 8]);
        bf16x8 al = ld_lds8(&QLo[it * 16 + ln][lq * 8]);
        bf16x8 bh = ld_lds8(&KH[jt * 16 + ln][lq * 8]);
        bf16x8 bl = ld_lds8(&KLo[jt * 16 + ln][lq * 8]);
        f32x4 d = (f32x4)0.f;
        d = __builtin_amdgcn_mfma_f32_16x16x32_bf16(al, bh, d, 0, 0, 0);
        d = __builtin_amdgcn_mfma_f32_16x16x32_bf16(ah, bl, d, 0, 0, 0);
        d = __builtin_amdgcn_mfma_f32_16x16x32_bf16(ah, bh, d, 0, 0, 0);
#pragma unroll
        for (int r = 0; r < 4; r++)
            EL[it * 16 + lq * 4 + r][jt * 16 + ln] = d[r];
    }
    __syncthreads();

    const int sub = t & 7;
    for (int pi = t >> 3; pi < 96; pi += 32) {
        float ev[12];
        float mx = -3.0e38f;
#pragma unroll
        for (int k = 0; k < 12; k++) {
            int j = sub + 8 * k;
            float e = EL[pi][j];
            if (j == pi) e = -3.0e38f;
            ev[k] = e;
            mx = fmaxf(mx, e);
        }
#pragma unroll
        for (int k = 1; k < 8; k <<= 1) mx = fmaxf(mx, __shfl_xor(mx, k, 8));
        float ss = 0.f;
#pragma unroll
        for (int k = 0; k < 12; k++) ss += __expf(ev[k] - mx);
#pragma unroll
        for (int k = 1; k < 8; k <<= 1) ss += __shfl_xor(ss, k, 8);
        if (sub == 0) {
            Sm[bP + (size_t)pi * kW + w] = mx;
            Si[bP + (size_t)pi * kW + w] = ss;
        }
    }
}

// ---------------------------------------------------------------------------
// Kernel B: pass1 (row tiles). grid (3, H, B), block 256.  (unchanged R13 v3)
// ---------------------------------------------------------------------------
__global__ __launch_bounds__(256) void cc_pass1(
    const __hip_bfloat16* __restrict__ Qbh, const __hip_bfloat16* __restrict__ Qbl,
    const __hip_bfloat16* __restrict__ Kbh, const __hip_bfloat16* __restrict__ Kbl,
    const __hip_bfloat16* __restrict__ Vhw,
    const float* __restrict__ res_in, const float* __restrict__ gamma_p,
    __hip_bfloat16* __restrict__ Zb, float* __restrict__ Sm, float* __restrict__ Si,
    int s_off)
{
    __shared__ __align__(16) __hip_bfloat16 QH[32][36], QLo[32][36];
    __shared__ __align__(16) __hip_bfloat16 KH[96][36], KLo[96][36];
    __shared__ __align__(16) float EL[32][97];
    __shared__ __align__(16) __hip_bfloat16 attL[32][100];
    const int wt = blockIdx.x, h = blockIdx.y, b = blockIdx.z;
    const int w0 = wt * 32;
    const int t = threadIdx.x;
    const size_t bP = (size_t)b * kP;

    {
        int row = t >> 3, ch = (t & 7) * 4;
        size_t g = (bP + (size_t)h * kW + w0 + row) * kCq + ch;
        *(ushort4*)&QH[row][ch]  = *(const ushort4*)&Qbh[g];
        *(ushort4*)&QLo[row][ch] = *(const ushort4*)&Qbl[g];
    }
    for (int idx = t; idx < 768; idx += 256) {
        int row = idx >> 3, ch = (idx & 7) * 4;
        size_t g = (bP + (size_t)h * kW + row) * kCq + ch;
        *(ushort4*)&KH[row][ch]  = *(const ushort4*)&Kbh[g];
        *(ushort4*)&KLo[row][ch] = *(const ushort4*)&Kbl[g];
    }
    __syncthreads();

    const int wv = t >> 6, l = t & 63, ln = l & 15, lq = l >> 4;
#pragma unroll
    for (int s = 0; s < 3; s++) {
        int tile = wv * 3 + s, it = tile / 6, jt = tile % 6;
        bf16x8 ah = ld_lds8(&QH[it * 16 + ln][lq * 8]);
        bf16x8 al = ld_lds8(&QLo[it * 16 + ln][lq * 8]);
        bf16x8 bh = ld_lds8(&KH[jt * 16 + ln][lq * 8]);
        bf16x8 bl = ld_lds8(&KLo[jt * 16 + ln][lq * 8]);
        f32x4 d = (f32x4)0.f;
        d = __builtin_amdgcn_mfma_f32_16x16x32_bf16(al, bh, d, 0, 0, 0);
        d = __builtin_amdgcn_mfma_f32_16x16x32_bf16(ah, bl, d, 0, 0, 0);
        d = __builtin_amdgcn_mfma_f32_16x16x32_bf16(ah, bh, d, 0, 0, 0);
#pragma unroll
        for (int r = 0; r < 4; r++)
            EL[it * 16 + lq * 4 + r][jt * 16 + ln] = d[r];
    }
    __syncthreads();

    {
        const int pi = t >> 3, sub = t & 7;
        size_t sidx = bP + (size_t)h * kW + w0 + pi;
        float mH = Sm[sidx], sH = Si[sidx];
        float ev[12];
        float mx = mH;
#pragma unroll
        for (int k = 0; k < 12; k++) {
            float e = EL[pi][sub + 8 * k];
            ev[k] = e;
            mx = fmaxf(mx, e);
        }
#pragma unroll
        for (int k = 1; k < 8; k <<= 1) mx = fmaxf(mx, __shfl_xor(mx, k, 8));
        float ss = 0.f;
#pragma unroll
        for (int k = 0; k < 12; k++) { float e = __expf(ev[k] - mx); ev[k] = e; ss += e; }
#pragma unroll
        for (int k = 1; k < 8; k <<= 1) ss += __shfl_xor(ss, k, 8);
        float stot = ss + sH * __expf(mH - mx);
        float inv = 1.0f / stot;
        if (sub == 0) { Sm[sidx] = mx; Si[sidx] = inv; }
#pragma unroll
        for (int k = 0; k < 12; k++)
            attL[pi][sub + 8 * k] = __float2bfloat16(ev[k] * inv);
    }
    __syncthreads();

    const float* __restrict__ res = res_in + (size_t)b * kC * kP + (size_t)h * kW + w0;
    float4 rsv[4][2];
#pragma unroll
    for (int c4 = 0; c4 < 4; c4++) {
        const int c = (wv * 4 + c4) * 16 + ln;
#pragma unroll
        for (int it = 0; it < 2; it++)
            rsv[c4][it] = *(const float4*)&res[(size_t)c * kP + it * 16 + lq * 4];
    }

    bf16x8 aF[2][3];
#pragma unroll
    for (int it = 0; it < 2; it++)
#pragma unroll
        for (int j3 = 0; j3 < 3; j3++)
            aF[it][j3] = ld_lds8(&attL[it * 16 + ln][j3 * 32 + lq * 8]);

    f32x4 acc[2][4];
#pragma unroll
    for (int it = 0; it < 2; it++)
#pragma unroll
        for (int c4 = 0; c4 < 4; c4++) acc[it][c4] = (f32x4)0.f;

#pragma unroll
    for (int c4 = 0; c4 < 4; c4++) {
        const int c = (wv * 4 + c4) * 16 + ln;
        const __hip_bfloat16* vr = Vhw + ((size_t)b * kC + c) * kP + (size_t)h * kW;
        bf16x8 bF0 = *(const bf16x8*)&vr[lq * 8];
        bf16x8 bF1 = *(const bf16x8*)&vr[32 + lq * 8];
        bf16x8 bF2 = *(const bf16x8*)&vr[64 + lq * 8];
#pragma unroll
        for (int it = 0; it < 2; it++) {
            acc[it][c4] = __builtin_amdgcn_mfma_f32_16x16x32_bf16(aF[it][0], bF0, acc[it][c4], 0, 0, 0);
            acc[it][c4] = __builtin_amdgcn_mfma_f32_16x16x32_bf16(aF[it][1], bF1, acc[it][c4], 0, 0, 0);
            acc[it][c4] = __builtin_amdgcn_mfma_f32_16x16x32_bf16(aF[it][2], bF2, acc[it][c4], 0, 0, 0);
        }
    }

    const float gamma = gamma_p[0];
#pragma unroll
    for (int c4 = 0; c4 < 4; c4++) {
        const int c = (wv * 4 + c4) * 16 + ln;
#pragma unroll
        for (int it = 0; it < 2; it++) {
            const float* rp = (const float*)&rsv[c4][it];
#pragma unroll
            for (int r = 0; r < 4; r++) {
                int i = it * 16 + lq * 4 + r;
                float z = gamma * acc[it][c4][r] + rp[r];
                Zb[(bP + (size_t)h * kW + w0 + i) * 512 + s_off + c] = __float2bfloat16(z);
            }
        }
    }
}

// ---------------------------------------------------------------------------
// Kernel C: pass2 (column tiles). grid (3, W, B), block 256.
// v4: VL staging ELIMINATED — outH B-fragments read directly from Vcol
// [b][c][w][h] as 16B loads (mirrors pass1's proven PV phase; 16 ch x 64B
// contiguous segments per instruction). Same V values, same MFMA order ->
// bitwise-identical. LDS 74.8 KB -> 24.8 KB.
// ---------------------------------------------------------------------------
__global__ __launch_bounds__(256) void cc_pass2(
    const __hip_bfloat16* __restrict__ Qbh, const __hip_bfloat16* __restrict__ Qbl,
    const __hip_bfloat16* __restrict__ Kbh, const __hip_bfloat16* __restrict__ Kbl,
    const __hip_bfloat16* __restrict__ Vcol,
    const float* __restrict__ gamma_p, __hip_bfloat16* __restrict__ Zb,
    const float* __restrict__ Sm, const float* __restrict__ Si, int s_off)
{
    __shared__ __align__(16) __hip_bfloat16 QH[32][36], QLo[32][36];
    __shared__ __align__(16) __hip_bfloat16 KH[96][36], KLo[96][36];
    __shared__ __align__(16) __hip_bfloat16 attL[32][100];
    const int ht = blockIdx.x, w = blockIdx.y, b = blockIdx.z;
    const int h0 = ht * 32;
    const int t = threadIdx.x;
    const size_t bP = (size_t)b * kP;

    {
        int row = t >> 3, ch = (t & 7) * 4;
        size_t g = (bP + (size_t)(h0 + row) * kW + w) * kCq + ch;
        *(ushort4*)&QH[row][ch]  = *(const ushort4*)&Qbh[g];
        *(ushort4*)&QLo[row][ch] = *(const ushort4*)&Qbl[g];
    }
    for (int idx = t; idx < 768; idx += 256) {
        int row = idx >> 3, ch = (idx & 7) * 4;
        size_t g = (bP + (size_t)row * kW + w) * kCq + ch;
        *(ushort4*)&KH[row][ch]  = *(const ushort4*)&Kbh[g];
        *(ushort4*)&KLo[row][ch] = *(const ushort4*)&Kbl[g];
    }
    __syncthreads();

    const int wv = t >> 6, l = t & 63, ln = l & 15, lq = l >> 4;
#pragma unroll
    for (int s = 0; s < 3; s++) {
        int tile = wv * 3 + s, it = tile / 6, jt = tile % 6;
        bf16x8 ah = ld_lds8(&QH[it * 16 + ln][lq * 8]);
        bf16x8 al = ld_lds8(&QLo[it * 16 + ln][lq * 8]);
        bf16x8 bh = ld_lds8(&KH[jt * 16 + ln][lq * 8]);
        bf16x8 bl = ld_lds8(&KLo[jt * 16 + ln][lq * 8]);
        f32x4 d = (f32x4)0.f;
        d = __builtin_amdgcn_mfma_f32_16x16x32_bf16(al, bh, d, 0, 0, 0);
        d = __builtin_amdgcn_mfma_f32_16x16x32_bf16(ah, bl, d, 0, 0, 0);
        d = __builtin_amdgcn_mfma_f32_16x16x32_bf16(ah, bh, d, 0, 0, 0);
        const int j = jt * 16 + ln;
#pragma unroll
        for (int r = 0; r < 4; r++) {
            int i = it * 16 + lq * 4 + r;
            size_t sidx = bP + (size_t)(h0 + i) * kW + w;
            float m = Sm[sidx], inv = Si[sidx];
            float a = (j == h0 + i) ? 0.f : __expf(d[r] - m) * inv;
            attL[i][j] = __float2bfloat16(a);
        }
    }
    __syncthreads();

    bf16x8 aF[2][3];
#pragma unroll
    for (int it = 0; it < 2; it++)
#pragma unroll
        for (int j3 = 0; j3 < 3; j3++)
            aF[it][j3] = ld_lds8(&attL[it * 16 + ln][j3 * 32 + lq * 8]);

    f32x4 acc[2][4];
#pragma unroll
    for (int it = 0; it < 2; it++)
#pragma unroll
        for (int c4 = 0; c4 < 4; c4++) acc[it][c4] = (f32x4)0.f;

#pragma unroll
    for (int c4 = 0; c4 < 4; c4++) {
        const int c = (wv * 4 + c4) * 16 + ln;
        const __hip_bfloat16* vc = Vcol + ((size_t)b * kC + c) * kP + (size_t)w * kH;
        bf16x8 bF0 = *(const bf16x8*)&vc[lq * 8];
        bf16x8 bF1 = *(const bf16x8*)&vc[32 + lq * 8];
        bf16x8 bF2 = *(const bf16x8*)&vc[64 + lq * 8];
#pragma unroll
        for (int it = 0; it < 2; it++) {
            acc[it][c4] = __builtin_amdgcn_mfma_f32_16x16x32_bf16(aF[it][0], bF0, acc[it][c4], 0, 0, 0);
            acc[it][c4] = __builtin_amdgcn_mfma_f32_16x16x32_bf16(aF[it][1], bF1, acc[it][c4], 0, 0, 0);
            acc[it][c4] = __builtin_amdgcn_mfma_f32_16x16x32_bf16(aF[it][2], bF2, acc[it][c4], 0, 0, 0);
        }
    }

    const float gamma = gamma_p[0];
#pragma unroll
    for (int c4 = 0; c4 < 4; c4++) {
        const int c = (wv * 4 + c4) * 16 + ln;
#pragma unroll
        for (int it = 0; it < 2; it++) {
#pragma unroll
            for (int r = 0; r < 4; r++) {
                int i = it * 16 + lq * 4 + r;
                size_t zi = (bP + (size_t)(h0 + i) * kW + w) * 512 + s_off + c;
                float old = __bfloat162float(Zb[zi]);
                Zb[zi] = __float2bfloat16(old + gamma * acc[it][c4][r]);
            }
        }
    }
}

// ---------------------------------------------------------------------------
// Kernel W2: convert Wp [256][512] fp32 -> bf16 (into dead Qb region).
// ---------------------------------------------------------------------------
__global__ __launch_bounds__(256) void wp_convert(
    const float* __restrict__ Wp, __hip_bfloat16* __restrict__ Wpb)
{
    const int i = blockIdx.x * 256 + threadIdx.x;
    Wpb[i] = __float2bfloat16(Wp[i]);
}

// ---------------------------------------------------------------------------
// Kernel D v4 (best-known config, unchanged: ~167 us).
// ---------------------------------------------------------------------------
__global__ __launch_bounds__(256, 4) void dwpw(
    const __hip_bfloat16* __restrict__ Zb,
    const float* __restrict__ Wdw, const float* __restrict__ bd,
    const __hip_bfloat16* __restrict__ Wpb, const float* __restrict__ bp,
    float* __restrict__ out)
{
    __shared__ __align__(16) __hip_bfloat16 zs[16][520];   // 16640 B

    const int wt = blockIdx.x, h = blockIdx.y, b = blockIdx.z;
    const int w0 = wt * 16;
    const int t = threadIdx.x;
    const size_t bP = (size_t)b * kP;

    const int l = t & 63, wv = t >> 6;
    const int lo16 = l & 15, q = l >> 4;

    const bf16x8* __restrict__ Bb[4];
#pragma unroll
    for (int nt = 0; nt < 4; nt++)
        Bb[nt] = (const bf16x8*)(Wpb + (size_t)(wv * 64 + nt * 16 + lo16) * 512);

    {
        float wd0[9], wd1[9];
#pragma unroll
        for (int k = 0; k < 9; k++) {
            wd0[k] = Wdw[(size_t)(2 * t) * 9 + k];
            wd1[k] = Wdw[(size_t)(2 * t + 1) * 9 + k];
        }
        const float b0 = bd[2 * t], b1 = bd[2 * t + 1];
        const uint* __restrict__ Zp = (const uint*)Zb + bP * 256 + t;
        const bool rvm = (h > 0), rvp = (h < kH - 1);

#pragma unroll
        for (int j0 = 0; j0 < 16; j0 += 8) {
            uint raw[10][3];
#pragma unroll
            for (int col = 0; col < 10; col++) {
                const int ww = w0 + j0 - 1 + col;
                const bool cv = (ww >= 0) && (ww < kW);
#pragma unroll
                for (int r = 0; r < 3; r++) {
                    const bool v = cv && (r == 1 || (r == 0 ? rvm : rvp));
                    raw[col][r] = v ? Zp[(size_t)((h + r - 1) * kW + ww) * 256] : 0u;
                }
            }
            float2 wfc[10][3];
#pragma unroll
            for (int col = 0; col < 10; col++)
#pragma unroll
                for (int r = 0; r < 3; r++) {
                    __hip_bfloat162 z2 = *(const __hip_bfloat162*)&raw[col][r];
                    wfc[col][r] = __bfloat1622float2(z2);
                }
#pragma unroll
            for (int j = 0; j < 8; j++) {
                float a0 = b0, a1 = b1;
#pragma unroll
                for (int r = 0; r < 3; r++) {
#pragma unroll
                    for (int dw = 0; dw < 3; dw++) {
                        const float2 z = wfc[j + dw][r];
                        const int k = r * 3 + dw;
                        a0 += wd0[k] * z.x;
                        a1 += wd1[k] * z.y;
                    }
                }
                __hip_bfloat162 pz;
                pz.x = __float2bfloat16(a0);
                pz.y = __float2bfloat16(a1);
                ((__hip_bfloat162*)&zs[j0 + j][0])[t] = pz;
            }
        }
    }

    bf16x8 wbuf[4][4];
#pragma unroll
    for (int kp = 0; kp < 4; kp++)
#pragma unroll
        for (int nt = 0; nt < 4; nt++)
            wbuf[kp][nt] = Bb[nt][kp * 4 + q];

    __syncthreads();

    f32x4 acc[4];
#pragma unroll
    for (int nt = 0; nt < 4; nt++) acc[nt] = (f32x4)0.f;

#pragma unroll
    for (int kc = 0; kc < 16; kc++) {
        const int s = kc & 3;
        bf16x8 a0 = ld_lds8(&zs[lo16][kc * 32 + q * 8]);
        bf16x8 wcur[4];
#pragma unroll
        for (int nt = 0; nt < 4; nt++) wcur[nt] = wbuf[s][nt];
        if (kc < 12) {
#pragma unroll
            for (int nt = 0; nt < 4; nt++)
                wbuf[s][nt] = Bb[nt][(kc + 4) * 4 + q];
        }
#pragma unroll
        for (int nt = 0; nt < 4; nt++)
            acc[nt] = __builtin_amdgcn_mfma_f32_16x16x32_bf16(a0, wcur[nt], acc[nt], 0, 0, 0);
    }

#pragma unroll
    for (int nt = 0; nt < 4; nt++) {
        const int ol = wv * 64 + nt * 16 + lo16;
        const float bias = bp[ol];
        float4 rv;
        float v0 = acc[nt][0] + bias; rv.x = v0 > 0.f ? v0 : 0.01f * v0;
        float v1 = acc[nt][1] + bias; rv.y = v1 > 0.f ? v1 : 0.01f * v1;
        float v2 = acc[nt][2] + bias; rv.z = v2 > 0.f ? v2 : 0.01f * v2;
        float v3 = acc[nt][3] + bias; rv.w = v3 > 0.f ? v3 : 0.01f * v3;
        *(float4*)&out[((size_t)b * 256 + ol) * kP + (size_t)h * kW + w0 + q * 4] = rv;
    }
}

// ---------------------------------------------------------------------------
extern "C" void kernel_launch(void* const* d_in, const int* in_sizes, int n_in,
                              void* d_out, int out_size, void* d_ws, size_t ws_size,
                              hipStream_t stream)
{
    const float* x   = (const float*)d_in[0];
    const float* y   = (const float*)d_in[1];
    const float* Wq  = (const float*)d_in[2];
    const float* bq  = (const float*)d_in[3];
    const float* Wk  = (const float*)d_in[4];
    const float* bk  = (const float*)d_in[5];
    const float* Wv  = (const float*)d_in[6];
    const float* bv  = (const float*)d_in[7];
    const float* g1  = (const float*)d_in[8];
    const float* g2  = (const float*)d_in[9];
    const float* Wdw = (const float*)d_in[10];
    const float* bd  = (const float*)d_in[11];
    const float* Wp  = (const float*)d_in[12];
    const float* bp  = (const float*)d_in[13];
    float* out = (float*)d_out;

    // Workspace layout (94,961,664 B total — unchanged):
    //   Zb       : bf16 [8][9216][512]      = 75,497,472
    //   Qb hi/lo : bf16 2x[8][9216][32]     =  9,437,184
    //   Kb hi/lo : bf16 2x[8][9216][32]     =  9,437,184
    //   Sm, Si   : fp32 [8][9216]           =    294,912 each
    // V (bf16, two layouts) lives in d_out until dwpw:
    //   Vcol [8][256][96 w][96 h] @ +0 (replaces Vpm; written by vcol_tr),
    //   Vhw  [8][256][9216]       @ +37,748,736.
    // Wqkb/Wvb alias the (dead at qkv time) Sm region; Wpb aliases Qb region.
    char* wsb = (char*)d_ws;
    __hip_bfloat16* Zb  = (__hip_bfloat16*)wsb;
    __hip_bfloat16* Qbh = (__hip_bfloat16*)(wsb + 75497472);
    __hip_bfloat16* Qbl = Qbh + 2359296;
    __hip_bfloat16* Kbh = (__hip_bfloat16*)(wsb + 84934656);
    __hip_bfloat16* Kbl = Kbh + 2359296;
    float* Sm = (float*)(wsb + 94371840);
    float* Si = (float*)(wsb + 94666752);
    __hip_bfloat16* Wqkb = (__hip_bfloat16*)Sm;
    __hip_bfloat16* Wvb  = ((__hip_bfloat16*)Sm) + 16384;
    __hip_bfloat16* Wpb  = (__hip_bfloat16*)(wsb + 75497472);  // dead Qb region
    __hip_bfloat16* Vcol = (__hip_bfloat16*)d_out;
    __hip_bfloat16* Vhw  = Vcol + 18874368;

    // stream 1: q,k from x; v from y; residual x; channels [0,256)
    hipLaunchKernelGGL(w_convert, dim3(320), dim3(256), 0, stream,
                       Wq, Wk, Wv, Wqkb, Wvb);
    hipLaunchKernelGGL(qkv_mfma, dim3(kP / 64, kB), dim3(256), 0, stream,
                       x, y, Wqkb, Wvb, bq, bk, bv, Qbh, Qbl, Kbh, Kbl, Vhw);
    hipLaunchKernelGGL(vcol_tr, dim3(kB * kC), dim3(256), 0, stream, Vhw, Vcol);
    hipLaunchKernelGGL(cc_stats, dim3(kW, kB), dim3(256), 0, stream,
                       Qbh, Qbl, Kbh, Kbl, Sm, Si);
    hipLaunchKernelGGL(cc_pass1, dim3(kW / 32, kH, kB), dim3(256), 0, stream,
                       Qbh, Qbl, Kbh, Kbl, Vhw, x, g1, Zb, Sm, Si, 0);
    hipLaunchKernelGGL(cc_pass2, dim3(kH / 32, kW, kB), dim3(256), 0, stream,
                       Qbh, Qbl, Kbh, Kbl, Vcol, g1, Zb, Sm, Si, 0);
    // stream 2: q,k from y; v from x; residual y; channels [256,512)
    hipLaunchKernelGGL(w_convert, dim3(320), dim3(256), 0, stream,
                       Wq, Wk, Wv, Wqkb, Wvb);
    hipLaunchKernelGGL(qkv_mfma, dim3(kP / 64, kB), dim3(256), 0, stream,
                       y, x, Wqkb, Wvb, bq, bk, bv, Qbh, Qbl, Kbh, Kbl, Vhw);
    hipLaunchKernelGGL(vcol_tr, dim3(kB * kC), dim3(256), 0, stream, Vhw, Vcol);
    hipLaunchKernelGGL(cc_stats, dim3(kW, kB), dim3(256), 0, stream,
                       Qbh, Qbl, Kbh, Kbl, Sm, Si);
    hipLaunchKernelGGL(cc_pass1, dim3(kW / 32, kH, kB), dim3(256), 0, stream,
                       Qbh, Qbl, Kbh, Kbl, Vhw, y, g2, Zb, Sm, Si, 256);
    hipLaunchKernelGGL(cc_pass2, dim3(kH / 32, kW, kB), dim3(256), 0, stream,
                       Qbh, Qbl, Kbh, Kbl, Vcol, g2, Zb, Sm, Si, 256);
    // convert Wp to bf16 (Qb region dead now)
    hipLaunchKernelGGL(wp_convert, dim3(512), dim3(256), 0, stream, Wp, Wpb);
    // fused depthwise + pointwise MFMA + leaky relu (overwrites d_out)
    hipLaunchKernelGGL(dwpw, dim3(kW / 16, kH, kB), dim3(256), 0, stream,
                       Zb, Wdw, bd, Wpb, bp, out);
}

// Round 15
// 813.378 us; speedup vs baseline: 1.0104x; 1.0104x over previous
//
#include <hip/hip_runtime.h>
#include <hip/hip_bf16.h>

constexpr int kB  = 8;
constexpr int kC  = 256;
constexpr int kCq = 32;
constexpr int kH  = 96;
constexpr int kW  = 96;
constexpr int kP  = kH * kW;      // 9216

using bf16x8 = __attribute__((ext_vector_type(8))) short;
using bf16x4 = __attribute__((ext_vector_type(4))) short;
using f32x4  = __attribute__((ext_vector_type(4))) float;

// load 8 bf16 from 8B-aligned LDS as two b64 reads
__device__ inline bf16x8 ld_lds8(const __hip_bfloat16* p) {
    bf16x4 lo = *(const bf16x4*)p;
    bf16x4 hi = *(const bf16x4*)(p + 4);
    return __builtin_shufflevector(lo, hi, 0, 1, 2, 3, 4, 5, 6, 7);
}

// async 16B global->LDS copy (per-lane global addr, wave-uniform LDS base)
__device__ inline void async_copy16(const void* g, void* l) {
    __builtin_amdgcn_global_load_lds(
        (const __attribute__((address_space(1))) unsigned int*)g,
        (__attribute__((address_space(3))) unsigned int*)l, 16, 0, 0);
}

// ---------------------------------------------------------------------------
// Kernel W1: convert Wq+Wk -> Wqkb [64][256] bf16, Wv -> Wvb [256][256] bf16.
// ---------------------------------------------------------------------------
__global__ __launch_bounds__(256) void w_convert(
    const float* __restrict__ Wq, const float* __restrict__ Wk,
    const float* __restrict__ Wv,
    __hip_bfloat16* __restrict__ Wqkb, __hip_bfloat16* __restrict__ Wvb)
{
    const int i = blockIdx.x * 256 + threadIdx.x;
    if (i < 8192)       Wqkb[i] = __float2bfloat16(Wq[i]);
    else if (i < 16384) Wqkb[i] = __float2bfloat16(Wk[i - 8192]);
    else                Wvb[i - 16384] = __float2bfloat16(Wv[i - 16384]);
}

// ---------------------------------------------------------------------------
// Kernel A v5: q/k/v projection GEMM via bf16 MFMA.
// Async global_load_lds input staging (zero staging registers) + all 20
// weight fragments batched before the MFMAs (one L2 round-trip per K-step).
// ---------------------------------------------------------------------------
__global__ __launch_bounds__(256, 2) void qkv_mfma(
    const float* __restrict__ in_qk, const float* __restrict__ in_v,
    const __hip_bfloat16* __restrict__ Wqkb, const __hip_bfloat16* __restrict__ Wvb,
    const float* __restrict__ bq, const float* __restrict__ bk,
    const float* __restrict__ bv,
    __hip_bfloat16* __restrict__ Qbh, __hip_bfloat16* __restrict__ Qbl,
    __hip_bfloat16* __restrict__ Kbh, __hip_bfloat16* __restrict__ Kbl,
    __hip_bfloat16* __restrict__ Vpm, __hip_bfloat16* __restrict__ Vhw)
{
    __shared__ __align__(16) char smem[34816];
    float* stg = (float*)smem;
    __hip_bfloat16* vt = (__hip_bfloat16*)smem;

    const int b = blockIdx.y, t = threadIdx.x;
    const int wv = t >> 6, l = t & 63;
    const int n = l & 15, q = l >> 4;
    const int p0 = blockIdx.x * 64;
    const int p  = p0 + wv * 16 + n;
    const size_t bP = (size_t)b * kP;

    const float* __restrict__ xq = in_qk + (size_t)b * kC * kP + p0;
    const float* __restrict__ xv = in_v  + (size_t)b * kC * kP + p0;

    f32x4 acc[20];
#pragma unroll
    for (int i = 0; i < 20; i++) acc[i] = (f32x4)0.f;

    const int lrow = l >> 4, lpx = (l & 15) * 4;
#define STAGE_CHUNK(kc, buf)                                                   \
    {                                                                          \
        const size_t cb = (size_t)(kc) * 32;                                   \
        float* dq = stg + (size_t)(buf) * 4096;                                \
        float* dv = dq + 2048;                                                 \
        _Pragma("unroll")                                                      \
        for (int j = 0; j < 2; j++) {                                          \
            const int r0 = wv * 8 + j * 4;                                     \
            async_copy16(&xq[(cb + r0 + lrow) * kP + lpx], &dq[r0 * 64]);      \
            async_copy16(&xv[(cb + r0 + lrow) * kP + lpx], &dv[r0 * 64]);      \
        }                                                                      \
    }

    STAGE_CHUNK(0, 0);
    __syncthreads();

    int cur = 0;
    for (int kc = 0; kc < 8; kc++) {
        if (kc < 7) STAGE_CHUNK(kc + 1, cur ^ 1);

        const int c0 = kc * 32 + q * 8;

        bf16x8 wq[4], wv2[16];
#pragma unroll
        for (int mt = 0; mt < 4; mt++)
            wq[mt] = *(const bf16x8*)(Wqkb + ((mt * 16 + n) << 8) + c0);
#pragma unroll
        for (int mt = 0; mt < 16; mt++)
            wv2[mt] = *(const bf16x8*)(Wvb + ((mt * 16 + n) << 8) + c0);

        const float* __restrict__ sqf = stg + (size_t)cur * 4096;
        const float* __restrict__ svf = sqf + 2048;
        const int pl = wv * 16 + n;
        union { bf16x8 v; __hip_bfloat16 h[8]; } bfq, bfv;
#pragma unroll
        for (int j = 0; j < 8; j++)
            bfq.h[j] = __float2bfloat16(sqf[(q * 8 + j) * 64 + pl]);
#pragma unroll
        for (int j = 0; j < 8; j++)
            bfv.h[j] = __float2bfloat16(svf[(q * 8 + j) * 64 + pl]);

#pragma unroll
        for (int mt = 0; mt < 4; mt++)
            acc[mt] = __builtin_amdgcn_mfma_f32_16x16x32_bf16(wq[mt], bfq.v, acc[mt], 0, 0, 0);
#pragma unroll
        for (int mt = 0; mt < 16; mt++)
            acc[4 + mt] = __builtin_amdgcn_mfma_f32_16x16x32_bf16(wv2[mt], bfv.v, acc[4 + mt], 0, 0, 0);

        __syncthreads();
        cur ^= 1;
    }
#undef STAGE_CHUNK

#pragma unroll
    for (int mt = 0; mt < 2; mt++) {
        float4 bias = *(const float4*)&bq[mt * 16 + q * 4];
        float vv[4] = { acc[mt][0] + bias.x, acc[mt][1] + bias.y,
                        acc[mt][2] + bias.z, acc[mt][3] + bias.w };
        union { ushort4 u; __hip_bfloat16 h[4]; } hi, lo;
#pragma unroll
        for (int r = 0; r < 4; r++) {
            __hip_bfloat16 h = __float2bfloat16(vv[r]);
            hi.h[r] = h;
            lo.h[r] = __float2bfloat16(vv[r] - __bfloat162float(h));
        }
        *(ushort4*)&Qbh[(bP + p) * kCq + mt * 16 + q * 4] = hi.u;
        *(ushort4*)&Qbl[(bP + p) * kCq + mt * 16 + q * 4] = lo.u;
    }
#pragma unroll
    for (int mt = 2; mt < 4; mt++) {
        float4 bias = *(const float4*)&bk[(mt - 2) * 16 + q * 4];
        float vv[4] = { acc[mt][0] + bias.x, acc[mt][1] + bias.y,
                        acc[mt][2] + bias.z, acc[mt][3] + bias.w };
        union { ushort4 u; __hip_bfloat16 h[4]; } hi, lo;
#pragma unroll
        for (int r = 0; r < 4; r++) {
            __hip_bfloat16 h = __float2bfloat16(vv[r]);
            hi.h[r] = h;
            lo.h[r] = __float2bfloat16(vv[r] - __bfloat162float(h));
        }
        *(ushort4*)&Kbh[(bP + p) * kCq + (mt - 2) * 16 + q * 4] = hi.u;
        *(ushort4*)&Kbl[(bP + p) * kCq + (mt - 2) * 16 + q * 4] = lo.u;
    }

#pragma unroll
    for (int mt = 0; mt < 16; mt++) {
        float4 bias = *(const float4*)&bv[mt * 16 + q * 4];
        float vv[4] = { acc[4 + mt][0] + bias.x, acc[4 + mt][1] + bias.y,
                        acc[4 + mt][2] + bias.z, acc[4 + mt][3] + bias.w };
        union { ushort4 u; __hip_bfloat16 h[4]; } pm;
#pragma unroll
        for (int r = 0; r < 4; r++) pm.h[r] = __float2bfloat16(vv[r]);
        *(ushort4*)&Vpm[(bP + p) * kC + mt * 16 + q * 4] = pm.u;
#pragma unroll
        for (int r = 0; r < 4; r++)
            vt[(mt * 16 + q * 4 + r) * 68 + wv * 16 + n] = pm.h[r];
    }
    __syncthreads();

    {
        __hip_bfloat16* dst = Vhw + ((size_t)b * kC + t) * kP + p0;
#pragma unroll
        for (int j = 0; j < 8; j++) {
            bf16x8 row = ld_lds8(&vt[t * 68 + j * 8]);
            *(bf16x8*)&dst[j * 8] = row;
        }
    }
}

// ---------------------------------------------------------------------------
// Kernel S: eH stats per column. grid (W, B), block 256.
// ---------------------------------------------------------------------------
__global__ __launch_bounds__(256) void cc_stats(
    const __hip_bfloat16* __restrict__ Qbh, const __hip_bfloat16* __restrict__ Qbl,
    const __hip_bfloat16* __restrict__ Kbh, const __hip_bfloat16* __restrict__ Kbl,
    float* __restrict__ Sm, float* __restrict__ Si)
{
    __shared__ __align__(16) __hip_bfloat16 QH[96][36], QLo[96][36];
    __shared__ __align__(16) __hip_bfloat16 KH[96][36], KLo[96][36];
    __shared__ __align__(16) float EL[96][97];
    const int w = blockIdx.x, b = blockIdx.y;
    const int t = threadIdx.x;
    const size_t bP = (size_t)b * kP;

    for (int idx = t; idx < 768; idx += 256) {
        int row = idx >> 3, ch = (idx & 7) * 4;
        size_t g = (bP + (size_t)row * kW + w) * kCq + ch;
        *(ushort4*)&QH[row][ch]  = *(const ushort4*)&Qbh[g];
        *(ushort4*)&QLo[row][ch] = *(const ushort4*)&Qbl[g];
        *(ushort4*)&KH[row][ch]  = *(const ushort4*)&Kbh[g];
        *(ushort4*)&KLo[row][ch] = *(const ushort4*)&Kbl[g];
    }
    __syncthreads();

    const int wv = t >> 6, l = t & 63, ln = l & 15, lq = l >> 4;
#pragma unroll
    for (int s = 0; s < 9; s++) {
        int tile = wv * 9 + s, it = tile / 6, jt = tile % 6;
        bf16x8 ah = ld_lds8(&QH[it * 16 + ln][lq * 8]);
        bf16x8 al = ld_lds8(&QLo[it * 16 + ln][lq * 8]);
        bf16x8 bh = ld_lds8(&KH[jt * 16 + ln][lq * 8]);
        bf16x8 bl = ld_lds8(&KLo[jt * 16 + ln][lq * 8]);
        f32x4 d = (f32x4)0.f;
        d = __builtin_amdgcn_mfma_f32_16x16x32_bf16(al, bh, d, 0, 0, 0);
        d = __builtin_amdgcn_mfma_f32_16x16x32_bf16(ah, bl, d, 0, 0, 0);
        d = __builtin_amdgcn_mfma_f32_16x16x32_bf16(ah, bh, d, 0, 0, 0);
#pragma unroll
        for (int r = 0; r < 4; r++)
            EL[it * 16 + lq * 4 + r][jt * 16 + ln] = d[r];
    }
    __syncthreads();

    const int sub = t & 7;
    for (int pi = t >> 3; pi < 96; pi += 32) {
        float ev[12];
        float mx = -3.0e38f;
#pragma unroll
        for (int k = 0; k < 12; k++) {
            int j = sub + 8 * k;
            float e = EL[pi][j];
            if (j == pi) e = -3.0e38f;
            ev[k] = e;
            mx = fmaxf(mx, e);
        }
#pragma unroll
        for (int k = 1; k < 8; k <<= 1) mx = fmaxf(mx, __shfl_xor(mx, k, 8));
        float ss = 0.f;
#pragma unroll
        for (int k = 0; k < 12; k++) ss += __expf(ev[k] - mx);
#pragma unroll
        for (int k = 1; k < 8; k <<= 1) ss += __shfl_xor(ss, k, 8);
        if (sub == 0) {
            Sm[bP + (size_t)pi * kW + w] = mx;
            Si[bP + (size_t)pi * kW + w] = ss;
        }
    }
}

// ---------------------------------------------------------------------------
// Kernel B: pass1 (row tiles). grid (3, H, B), block 256.
// v3: rs LDS buffer eliminated — residual loaded directly into registers
// after the softmax barrier. LDS 37.2 KB.
// ---------------------------------------------------------------------------
__global__ __launch_bounds__(256) void cc_pass1(
    const __hip_bfloat16* __restrict__ Qbh, const __hip_bfloat16* __restrict__ Qbl,
    const __hip_bfloat16* __restrict__ Kbh, const __hip_bfloat16* __restrict__ Kbl,
    const __hip_bfloat16* __restrict__ Vhw,
    const float* __restrict__ res_in, const float* __restrict__ gamma_p,
    __hip_bfloat16* __restrict__ Zb, float* __restrict__ Sm, float* __restrict__ Si,
    int s_off)
{
    __shared__ __align__(16) __hip_bfloat16 QH[32][36], QLo[32][36];
    __shared__ __align__(16) __hip_bfloat16 KH[96][36], KLo[96][36];
    __shared__ __align__(16) float EL[32][97];
    __shared__ __align__(16) __hip_bfloat16 attL[32][100];
    const int wt = blockIdx.x, h = blockIdx.y, b = blockIdx.z;
    const int w0 = wt * 32;
    const int t = threadIdx.x;
    const size_t bP = (size_t)b * kP;

    {
        int row = t >> 3, ch = (t & 7) * 4;
        size_t g = (bP + (size_t)h * kW + w0 + row) * kCq + ch;
        *(ushort4*)&QH[row][ch]  = *(const ushort4*)&Qbh[g];
        *(ushort4*)&QLo[row][ch] = *(const ushort4*)&Qbl[g];
    }
    for (int idx = t; idx < 768; idx += 256) {
        int row = idx >> 3, ch = (idx & 7) * 4;
        size_t g = (bP + (size_t)h * kW + row) * kCq + ch;
        *(ushort4*)&KH[row][ch]  = *(const ushort4*)&Kbh[g];
        *(ushort4*)&KLo[row][ch] = *(const ushort4*)&Kbl[g];
    }
    __syncthreads();

    const int wv = t >> 6, l = t & 63, ln = l & 15, lq = l >> 4;
#pragma unroll
    for (int s = 0; s < 3; s++) {
        int tile = wv * 3 + s, it = tile / 6, jt = tile % 6;
        bf16x8 ah = ld_lds8(&QH[it * 16 + ln][lq * 8]);
        bf16x8 al = ld_lds8(&QLo[it * 16 + ln][lq * 8]);
        bf16x8 bh = ld_lds8(&KH[jt * 16 + ln][lq * 8]);
        bf16x8 bl = ld_lds8(&KLo[jt * 16 + ln][lq * 8]);
        f32x4 d = (f32x4)0.f;
        d = __builtin_amdgcn_mfma_f32_16x16x32_bf16(al, bh, d, 0, 0, 0);
        d = __builtin_amdgcn_mfma_f32_16x16x32_bf16(ah, bl, d, 0, 0, 0);
        d = __builtin_amdgcn_mfma_f32_16x16x32_bf16(ah, bh, d, 0, 0, 0);
#pragma unroll
        for (int r = 0; r < 4; r++)
            EL[it * 16 + lq * 4 + r][jt * 16 + ln] = d[r];
    }
    __syncthreads();

    {
        const int pi = t >> 3, sub = t & 7;
        size_t sidx = bP + (size_t)h * kW + w0 + pi;
        float mH = Sm[sidx], sH = Si[sidx];
        float ev[12];
        float mx = mH;
#pragma unroll
        for (int k = 0; k < 12; k++) {
            float e = EL[pi][sub + 8 * k];
            ev[k] = e;
            mx = fmaxf(mx, e);
        }
#pragma unroll
        for (int k = 1; k < 8; k <<= 1) mx = fmaxf(mx, __shfl_xor(mx, k, 8));
        float ss = 0.f;
#pragma unroll
        for (int k = 0; k < 12; k++) { float e = __expf(ev[k] - mx); ev[k] = e; ss += e; }
#pragma unroll
        for (int k = 1; k < 8; k <<= 1) ss += __shfl_xor(ss, k, 8);
        float stot = ss + sH * __expf(mH - mx);
        float inv = 1.0f / stot;
        if (sub == 0) { Sm[sidx] = mx; Si[sidx] = inv; }
#pragma unroll
        for (int k = 0; k < 12; k++)
            attL[pi][sub + 8 * k] = __float2bfloat16(ev[k] * inv);
    }
    __syncthreads();

    const float* __restrict__ res = res_in + (size_t)b * kC * kP + (size_t)h * kW + w0;
    float4 rsv[4][2];
#pragma unroll
    for (int c4 = 0; c4 < 4; c4++) {
        const int c = (wv * 4 + c4) * 16 + ln;
#pragma unroll
        for (int it = 0; it < 2; it++)
            rsv[c4][it] = *(const float4*)&res[(size_t)c * kP + it * 16 + lq * 4];
    }

    bf16x8 aF[2][3];
#pragma unroll
    for (int it = 0; it < 2; it++)
#pragma unroll
        for (int j3 = 0; j3 < 3; j3++)
            aF[it][j3] = ld_lds8(&attL[it * 16 + ln][j3 * 32 + lq * 8]);

    f32x4 acc[2][4];
#pragma unroll
    for (int it = 0; it < 2; it++)
#pragma unroll
        for (int c4 = 0; c4 < 4; c4++) acc[it][c4] = (f32x4)0.f;

#pragma unroll
    for (int c4 = 0; c4 < 4; c4++) {
        const int c = (wv * 4 + c4) * 16 + ln;
        const __hip_bfloat16* vr = Vhw + ((size_t)b * kC + c) * kP + (size_t)h * kW;
        bf16x8 bF0 = *(const bf16x8*)&vr[lq * 8];
        bf16x8 bF1 = *(const bf16x8*)&vr[32 + lq * 8];
        bf16x8 bF2 = *(const bf16x8*)&vr[64 + lq * 8];
#pragma unroll
        for (int it = 0; it < 2; it++) {
            acc[it][c4] = __builtin_amdgcn_mfma_f32_16x16x32_bf16(aF[it][0], bF0, acc[it][c4], 0, 0, 0);
            acc[it][c4] = __builtin_amdgcn_mfma_f32_16x16x32_bf16(aF[it][1], bF1, acc[it][c4], 0, 0, 0);
            acc[it][c4] = __builtin_amdgcn_mfma_f32_16x16x32_bf16(aF[it][2], bF2, acc[it][c4], 0, 0, 0);
        }
    }

    const float gamma = gamma_p[0];
#pragma unroll
    for (int c4 = 0; c4 < 4; c4++) {
        const int c = (wv * 4 + c4) * 16 + ln;
#pragma unroll
        for (int it = 0; it < 2; it++) {
            const float* rp = (const float*)&rsv[c4][it];
#pragma unroll
            for (int r = 0; r < 4; r++) {
                int i = it * 16 + lq * 4 + r;
                float z = gamma * acc[it][c4][r] + rp[r];
                Zb[(bP + (size_t)h * kW + w0 + i) * 512 + s_off + c] = __float2bfloat16(z);
            }
        }
    }
}

// ---------------------------------------------------------------------------
// Kernel C: pass2 (column tiles). grid (3, W, B), block 256.
// ---------------------------------------------------------------------------
__global__ __launch_bounds__(256) void cc_pass2(
    const __hip_bfloat16* __restrict__ Qbh, const __hip_bfloat16* __restrict__ Qbl,
    const __hip_bfloat16* __restrict__ Kbh, const __hip_bfloat16* __restrict__ Kbl,
    const __hip_bfloat16* __restrict__ Vpm,
    const float* __restrict__ gamma_p, __hip_bfloat16* __restrict__ Zb,
    const float* __restrict__ Sm, const float* __restrict__ Si, int s_off)
{
    __shared__ __align__(16) __hip_bfloat16 QH[32][36], QLo[32][36];
    __shared__ __align__(16) __hip_bfloat16 KH[96][36], KLo[96][36];
    __shared__ __align__(16) __hip_bfloat16 VL[96][260];
    __shared__ __align__(16) __hip_bfloat16 attL[32][100];
    const int ht = blockIdx.x, w = blockIdx.y, b = blockIdx.z;
    const int h0 = ht * 32;
    const int t = threadIdx.x;
    const size_t bP = (size_t)b * kP;

    {
        int row = t >> 3, ch = (t & 7) * 4;
        size_t g = (bP + (size_t)(h0 + row) * kW + w) * kCq + ch;
        *(ushort4*)&QH[row][ch]  = *(const ushort4*)&Qbh[g];
        *(ushort4*)&QLo[row][ch] = *(const ushort4*)&Qbl[g];
    }
    for (int idx = t; idx < 768; idx += 256) {
        int row = idx >> 3, ch = (idx & 7) * 4;
        size_t g = (bP + (size_t)row * kW + w) * kCq + ch;
        *(ushort4*)&KH[row][ch]  = *(const ushort4*)&Kbh[g];
        *(ushort4*)&KLo[row][ch] = *(const ushort4*)&Kbl[g];
    }
    for (int idx = t; idx < 96 * 32; idx += 256) {
        int j = idx >> 5, cg = (idx & 31) * 8;
        const ushort4* src = (const ushort4*)&Vpm[(bP + (size_t)j * kW + w) * kC + cg];
        ushort4 v0 = src[0], v1 = src[1];
        *(ushort4*)&VL[j][cg]     = v0;
        *(ushort4*)&VL[j][cg + 4] = v1;
    }
    __syncthreads();

    const int wv = t >> 6, l = t & 63, ln = l & 15, lq = l >> 4;
#pragma unroll
    for (int s = 0; s < 3; s++) {
        int tile = wv * 3 + s, it = tile / 6, jt = tile % 6;
        bf16x8 ah = ld_lds8(&QH[it * 16 + ln][lq * 8]);
        bf16x8 al = ld_lds8(&QLo[it * 16 + ln][lq * 8]);
        bf16x8 bh = ld_lds8(&KH[jt * 16 + ln][lq * 8]);
        bf16x8 bl = ld_lds8(&KLo[jt * 16 + ln][lq * 8]);
        f32x4 d = (f32x4)0.f;
        d = __builtin_amdgcn_mfma_f32_16x16x32_bf16(al, bh, d, 0, 0, 0);
        d = __builtin_amdgcn_mfma_f32_16x16x32_bf16(ah, bl, d, 0, 0, 0);
        d = __builtin_amdgcn_mfma_f32_16x16x32_bf16(ah, bh, d, 0, 0, 0);
        const int j = jt * 16 + ln;
#pragma unroll
        for (int r = 0; r < 4; r++) {
            int i = it * 16 + lq * 4 + r;
            size_t sidx = bP + (size_t)(h0 + i) * kW + w;
            float m = Sm[sidx], inv = Si[sidx];
            float a = (j == h0 + i) ? 0.f : __expf(d[r] - m) * inv;
            attL[i][j] = __float2bfloat16(a);
        }
    }
    __syncthreads();

    bf16x8 aF[2][3];
#pragma unroll
    for (int it = 0; it < 2; it++)
#pragma unroll
        for (int j3 = 0; j3 < 3; j3++)
            aF[it][j3] = ld_lds8(&attL[it * 16 + ln][j3 * 32 + lq * 8]);

    f32x4 acc[2][4];
#pragma unroll
    for (int it = 0; it < 2; it++)
#pragma unroll
        for (int c4 = 0; c4 < 4; c4++) acc[it][c4] = (f32x4)0.f;

#pragma unroll
    for (int c4 = 0; c4 < 4; c4++) {
        const int c = (wv * 4 + c4) * 16 + ln;
#pragma unroll
        for (int j3 = 0; j3 < 3; j3++) {
            union { bf16x8 v; __hip_bfloat16 h[8]; } bF;
#pragma unroll
            for (int jj = 0; jj < 8; jj++)
                bF.h[jj] = VL[j3 * 32 + lq * 8 + jj][c];
#pragma unroll
            for (int it = 0; it < 2; it++)
                acc[it][c4] = __builtin_amdgcn_mfma_f32_16x16x32_bf16(aF[it][j3], bF.v, acc[it][c4], 0, 0, 0);
        }
    }

    const float gamma = gamma_p[0];
#pragma unroll
    for (int c4 = 0; c4 < 4; c4++) {
        const int c = (wv * 4 + c4) * 16 + ln;
#pragma unroll
        for (int it = 0; it < 2; it++) {
#pragma unroll
            for (int r = 0; r < 4; r++) {
                int i = it * 16 + lq * 4 + r;
                size_t zi = (bP + (size_t)(h0 + i) * kW + w) * 512 + s_off + c;
                float old = __bfloat162float(Zb[zi]);
                Zb[zi] = __float2bfloat16(old + gamma * acc[it][c4][r]);
            }
        }
    }
}

// ---------------------------------------------------------------------------
// Kernel W2: convert Wp [256][512] fp32 -> bf16 (into dead Qb region).
// ---------------------------------------------------------------------------
__global__ __launch_bounds__(256) void wp_convert(
    const float* __restrict__ Wp, __hip_bfloat16* __restrict__ Wpb)
{
    const int i = blockIdx.x * 256 + threadIdx.x;
    Wpb[i] = __float2bfloat16(Wp[i]);
}

// ---------------------------------------------------------------------------
// Kernel D v4 (best-known config: ~167 us).
// Fused depthwise 3x3 + pointwise 512->256 MFMA + leaky relu.
// ---------------------------------------------------------------------------
__global__ __launch_bounds__(256, 4) void dwpw(
    const __hip_bfloat16* __restrict__ Zb,
    const float* __restrict__ Wdw, const float* __restrict__ bd,
    const __hip_bfloat16* __restrict__ Wpb, const float* __restrict__ bp,
    float* __restrict__ out)
{
    __shared__ __align__(16) __hip_bfloat16 zs[16][520];   // 16640 B

    const int wt = blockIdx.x, h = blockIdx.y, b = blockIdx.z;
    const int w0 = wt * 16;
    const int t = threadIdx.x;
    const size_t bP = (size_t)b * kP;

    const int l = t & 63, wv = t >> 6;
    const int lo16 = l & 15, q = l >> 4;

    const bf16x8* __restrict__ Bb[4];
#pragma unroll
    for (int nt = 0; nt < 4; nt++)
        Bb[nt] = (const bf16x8*)(Wpb + (size_t)(wv * 64 + nt * 16 + lo16) * 512);

    {
        float wd0[9], wd1[9];
#pragma unroll
        for (int k = 0; k < 9; k++) {
            wd0[k] = Wdw[(size_t)(2 * t) * 9 + k];
            wd1[k] = Wdw[(size_t)(2 * t + 1) * 9 + k];
        }
        const float b0 = bd[2 * t], b1 = bd[2 * t + 1];
        const uint* __restrict__ Zp = (const uint*)Zb + bP * 256 + t;
        const bool rvm = (h > 0), rvp = (h < kH - 1);

#pragma unroll
        for (int j0 = 0; j0 < 16; j0 += 8) {
            uint raw[10][3];
#pragma unroll
            for (int col = 0; col < 10; col++) {
                const int ww = w0 + j0 - 1 + col;
                const bool cv = (ww >= 0) && (ww < kW);
#pragma unroll
                for (int r = 0; r < 3; r++) {
                    const bool v = cv && (r == 1 || (r == 0 ? rvm : rvp));
                    raw[col][r] = v ? Zp[(size_t)((h + r - 1) * kW + ww) * 256] : 0u;
                }
            }
            float2 wfc[10][3];
#pragma unroll
            for (int col = 0; col < 10; col++)
#pragma unroll
                for (int r = 0; r < 3; r++) {
                    __hip_bfloat162 z2 = *(const __hip_bfloat162*)&raw[col][r];
                    wfc[col][r] = __bfloat1622float2(z2);
                }
#pragma unroll
            for (int j = 0; j < 8; j++) {
                float a0 = b0, a1 = b1;
#pragma unroll
                for (int r = 0; r < 3; r++) {
#pragma unroll
                    for (int dw = 0; dw < 3; dw++) {
                        const float2 z = wfc[j + dw][r];
                        const int k = r * 3 + dw;
                        a0 += wd0[k] * z.x;
                        a1 += wd1[k] * z.y;
                    }
                }
                __hip_bfloat162 pz;
                pz.x = __float2bfloat16(a0);
                pz.y = __float2bfloat16(a1);
                ((__hip_bfloat162*)&zs[j0 + j][0])[t] = pz;
            }
        }
    }

    bf16x8 wbuf[4][4];
#pragma unroll
    for (int kp = 0; kp < 4; kp++)
#pragma unroll
        for (int nt = 0; nt < 4; nt++)
            wbuf[kp][nt] = Bb[nt][kp * 4 + q];

    __syncthreads();

    f32x4 acc[4];
#pragma unroll
    for (int nt = 0; nt < 4; nt++) acc[nt] = (f32x4)0.f;

#pragma unroll
    for (int kc = 0; kc < 16; kc++) {
        const int s = kc & 3;
        bf16x8 a0 = ld_lds8(&zs[lo16][kc * 32 + q * 8]);
        bf16x8 wcur[4];
#pragma unroll
        for (int nt = 0; nt < 4; nt++) wcur[nt] = wbuf[s][nt];
        if (kc < 12) {
#pragma unroll
            for (int nt = 0; nt < 4; nt++)
                wbuf[s][nt] = Bb[nt][(kc + 4) * 4 + q];
        }
#pragma unroll
        for (int nt = 0; nt < 4; nt++)
            acc[nt] = __builtin_amdgcn_mfma_f32_16x16x32_bf16(a0, wcur[nt], acc[nt], 0, 0, 0);
    }

#pragma unroll
    for (int nt = 0; nt < 4; nt++) {
        const int ol = wv * 64 + nt * 16 + lo16;
        const float bias = bp[ol];
        float4 rv;
        float v0 = acc[nt][0] + bias; rv.x = v0 > 0.f ? v0 : 0.01f * v0;
        float v1 = acc[nt][1] + bias; rv.y = v1 > 0.f ? v1 : 0.01f * v1;
        float v2 = acc[nt][2] + bias; rv.z = v2 > 0.f ? v2 : 0.01f * v2;
        float v3 = acc[nt][3] + bias; rv.w = v3 > 0.f ? v3 : 0.01f * v3;
        *(float4*)&out[((size_t)b * 256 + ol) * kP + (size_t)h * kW + w0 + q * 4] = rv;
    }
}

// ---------------------------------------------------------------------------
extern "C" void kernel_launch(void* const* d_in, const int* in_sizes, int n_in,
                              void* d_out, int out_size, void* d_ws, size_t ws_size,
                              hipStream_t stream)
{
    const float* x   = (const float*)d_in[0];
    const float* y   = (const float*)d_in[1];
    const float* Wq  = (const float*)d_in[2];
    const float* bq  = (const float*)d_in[3];
    const float* Wk  = (const float*)d_in[4];
    const float* bk  = (const float*)d_in[5];
    const float* Wv  = (const float*)d_in[6];
    const float* bv  = (const float*)d_in[7];
    const float* g1  = (const float*)d_in[8];
    const float* g2  = (const float*)d_in[9];
    const float* Wdw = (const float*)d_in[10];
    const float* bd  = (const float*)d_in[11];
    const float* Wp  = (const float*)d_in[12];
    const float* bp  = (const float*)d_in[13];
    float* out = (float*)d_out;

    // Workspace layout (94,961,664 B total):
    //   Zb       : bf16 [8][9216][512]      = 75,497,472
    //   Qb hi/lo : bf16 2x[8][9216][32]     =  9,437,184
    //   Kb hi/lo : bf16 2x[8][9216][32]     =  9,437,184
    //   Sm, Si   : fp32 [8][9216]           =    294,912 each
    // V (bf16, two layouts) lives in d_out until dwpw:
    //   Vpm [8][9216][256] @ +0, Vhw [8][256][9216] @ +37,748,736.
    // Wqkb/Wvb alias the (dead at qkv time) Sm region; Wpb aliases Qb region.
    char* wsb = (char*)d_ws;
    __hip_bfloat16* Zb  = (__hip_bfloat16*)wsb;
    __hip_bfloat16* Qbh = (__hip_bfloat16*)(wsb + 75497472);
    __hip_bfloat16* Qbl = Qbh + 2359296;
    __hip_bfloat16* Kbh = (__hip_bfloat16*)(wsb + 84934656);
    __hip_bfloat16* Kbl = Kbh + 2359296;
    float* Sm = (float*)(wsb + 94371840);
    float* Si = (float*)(wsb + 94666752);
    __hip_bfloat16* Wqkb = (__hip_bfloat16*)Sm;
    __hip_bfloat16* Wvb  = ((__hip_bfloat16*)Sm) + 16384;
    __hip_bfloat16* Wpb  = (__hip_bfloat16*)(wsb + 75497472);  // dead Qb region
    __hip_bfloat16* Vpm  = (__hip_bfloat16*)d_out;
    __hip_bfloat16* Vhw  = Vpm + 18874368;

    // stream 1: q,k from x; v from y; residual x; channels [0,256)
    hipLaunchKernelGGL(w_convert, dim3(320), dim3(256), 0, stream,
                       Wq, Wk, Wv, Wqkb, Wvb);
    hipLaunchKernelGGL(qkv_mfma, dim3(kP / 64, kB), dim3(256), 0, stream,
                       x, y, Wqkb, Wvb, bq, bk, bv, Qbh, Qbl, Kbh, Kbl, Vpm, Vhw);
    hipLaunchKernelGGL(cc_stats, dim3(kW, kB), dim3(256), 0, stream,
                       Qbh, Qbl, Kbh, Kbl, Sm, Si);
    hipLaunchKernelGGL(cc_pass1, dim3(kW / 32, kH, kB), dim3(256), 0, stream,
                       Qbh, Qbl, Kbh, Kbl, Vhw, x, g1, Zb, Sm, Si, 0);
    hipLaunchKernelGGL(cc_pass2, dim3(kH / 32, kW, kB), dim3(256), 0, stream,
                       Qbh, Qbl, Kbh, Kbl, Vpm, g1, Zb, Sm, Si, 0);
    // stream 2: q,k from y; v from x; residual y; channels [256,512)
    hipLaunchKernelGGL(w_convert, dim3(320), dim3(256), 0, stream,
                       Wq, Wk, Wv, Wqkb, Wvb);
    hipLaunchKernelGGL(qkv_mfma, dim3(kP / 64, kB), dim3(256), 0, stream,
                       y, x, Wqkb, Wvb, bq, bk, bv, Qbh, Qbl, Kbh, Kbl, Vpm, Vhw);
    hipLaunchKernelGGL(cc_stats, dim3(kW, kB), dim3(256), 0, stream,
                       Qbh, Qbl, Kbh, Kbl, Sm, Si);
    hipLaunchKernelGGL(cc_pass1, dim3(kW / 32, kH, kB), dim3(256), 0, stream,
                       Qbh, Qbl, Kbh, Kbl, Vhw, y, g2, Zb, Sm, Si, 256);
    hipLaunchKernelGGL(cc_pass2, dim3(kH / 32, kW, kB), dim3(256), 0, stream,
                       Qbh, Qbl, Kbh, Kbl, Vpm, g2, Zb, Sm, Si, 256);
    // convert Wp to bf16 (Qb region dead now)
    hipLaunchKernelGGL(wp_convert, dim3(512), dim3(256), 0, stream, Wp, Wpb);
    // fused depthwise + pointwise MFMA + leaky relu (overwrites d_out)
    hipLaunchKernelGGL(dwpw, dim3(kW / 16, kH, kB), dim3(256), 0, stream,
                       Zb, Wdw, bd, Wpb, bp, out);
}